// Round 12
// baseline (325.606 us; speedup 1.0000x reference)
//
#include <hip/hip_runtime.h>
#include <math.h>

typedef __attribute__((ext_vector_type(2))) float f32x2;
typedef __attribute__((ext_vector_type(4))) float f32x4;

#define MAX_DELAY 128
#define INPUT 64
#define HIDDEN 128
#define HALF 64
#define OUT 64
#define BATCH 32
#define T 128
#define OUT_LEN 64
#define NTHR 512

static __device__ __forceinline__ f32x2 splat2(float v) { f32x2 r; r.x = v; r.y = v; return r; }
static __device__ __forceinline__ f32x4 splat4(float v) { f32x4 r; r.x = v; r.y = v; r.z = v; r.w = v; return r; }

// DPP cross-lane (1-cycle VALU).
template <int CTRL>
static __device__ __forceinline__ float dpp_movf(float v) {
    return __int_as_float(__builtin_amdgcn_update_dpp(
        0, __float_as_int(v), CTRL, 0xF, 0xF, true));
}
#define DPP_XOR1 0xB1  // quad_perm [1,0,3,2]
#define DPP_XOR2 0x4E  // quad_perm [2,3,0,1]
#define DPP_ROT1 0x39  // quad_perm [1,2,3,0] (lane i <- i+1 mod 4)
#define DPP_MIR8 0x141 // row_half_mirror

// msg LDS pad: stride-24 per 16 floats (conflict-free, x4-aligned)
#define PAD16(k) ((k) + (((k) >> 4) << 3))
// heads LDS pad: +4 floats per 32 -> quad streams hit disjoint bank groups
#define PADH(k)  ((k) + (((k) >> 5) << 2))

// Best structure (3 barriers, 8 waves) + BLEND SPLIT P1/P3:
//  d in [8,16) blended in P3 of step t (fills P3's idle issue slots under the
//  tau->sigmoid->head chain; tau_t is fresh there). d in [0,8) stays deferred
//  into P1 of t+1 (covers the heads-read LDS latency). P3 saves old buf2[8].x
//  (sv8) for P1's d=7 edge; tail_in for d=15 captured in P3 pre-update.
//  Math per-element bit-identical to the 243.9us best.
__global__ __attribute__((amdgpu_waves_per_eu(2, 2))) __launch_bounds__(NTHR)
void delayrnn_kernel(
    const float* __restrict__ x,        // (B, T, INPUT)
    const int*   __restrict__ lengths,  // (B)
    const float* __restrict__ Wm,       // (INPUT+HIDDEN, HIDDEN)
    const float* __restrict__ bm,       // (HIDDEN)
    const float* __restrict__ W1,       // (HIDDEN, HALF)
    const float* __restrict__ b1,       // (HALF)
    const float* __restrict__ W2,       // (HALF, 2*HIDDEN)
    const float* __restrict__ b2,       // (2*HIDDEN)
    const float* __restrict__ Wo,       // (HIDDEN, OUT)
    const float* __restrict__ bo,       // (OUT)
    float* __restrict__ out)            // (B, OUT_LEN, OUT)
{
    const int b   = blockIdx.x;
    const int tid = threadIdx.x;
    const int len = lengths[b];
    const int total = len + OUT_LEN;

    const int h  = tid >> 2, q  = tid & 3;   // channel h: quad of 4 lanes
    const int qq = q & 1,    qh = q >> 1;    // tau/mem roles within the quad
    const int k1 = tid >> 3, r1 = tid & 7;   // h1: 8 lanes/out
    const int co = tid >> 3, ro = tid & 7;   // out-proj: 8 lanes/out
    const int c2 = h + 128 * qh;             // qh=0: tau col, qh=1: mem col

    // ---- weights -> registers (all f32) ----
    f32x4 wmh[8];                       // msg heads-part: rows 64 + [q*32, q*32+32)
#pragma unroll
    for (int j = 0; j < 8; ++j) {
        wmh[j].x = Wm[(64 + q * 32 + 4 * j    ) * HIDDEN + h];
        wmh[j].y = Wm[(64 + q * 32 + 4 * j + 1) * HIDDEN + h];
        wmh[j].z = Wm[(64 + q * 32 + 4 * j + 2) * HIDDEN + h];
        wmh[j].w = Wm[(64 + q * 32 + 4 * j + 3) * HIDDEN + h];
    }
    f32x4 wmx[4];                       // msg x-part: rows [q*16, q*16+16)
#pragma unroll
    for (int j = 0; j < 4; ++j) {
        wmx[j].x = Wm[(q * 16 + 4 * j    ) * HIDDEN + h];
        wmx[j].y = Wm[(q * 16 + 4 * j + 1) * HIDDEN + h];
        wmx[j].z = Wm[(q * 16 + 4 * j + 2) * HIDDEN + h];
        wmx[j].w = Wm[(q * 16 + 4 * j + 3) * HIDDEN + h];
    }
    f32x4 w14[4];                       // h1: K-slice [r1*16, r1*16+16)
#pragma unroll
    for (int j = 0; j < 4; ++j) {
        w14[j].x = W1[(r1 * 16 + 4 * j    ) * HALF + k1];
        w14[j].y = W1[(r1 * 16 + 4 * j + 1) * HALF + k1];
        w14[j].z = W1[(r1 * 16 + 4 * j + 2) * HALF + k1];
        w14[j].w = W1[(r1 * 16 + 4 * j + 3) * HALF + k1];
    }
    f32x4 w24[8];                       // tau/mem: K-slice [qq*32, qq*32+32)
#pragma unroll
    for (int j = 0; j < 8; ++j) {
        w24[j].x = W2[(qq * 32 + 4 * j    ) * (2 * HIDDEN) + c2];
        w24[j].y = W2[(qq * 32 + 4 * j + 1) * (2 * HIDDEN) + c2];
        w24[j].z = W2[(qq * 32 + 4 * j + 2) * (2 * HIDDEN) + c2];
        w24[j].w = W2[(qq * 32 + 4 * j + 3) * (2 * HIDDEN) + c2];
    }
    f32x4 wo4[4];                       // out: K-slice [ro*16, ro*16+16)
#pragma unroll
    for (int m = 0; m < 4; ++m) {
        wo4[m].x = Wo[(ro * 16 + 4 * m    ) * OUT + co];
        wo4[m].y = Wo[(ro * 16 + 4 * m + 1) * OUT + co];
        wo4[m].z = Wo[(ro * 16 + 4 * m + 2) * OUT + co];
        wo4[m].w = Wo[(ro * 16 + 4 * m + 3) * OUT + co];
    }
    const float bm_r = bm[h];
    const float b1_r = b1[k1];
    const float b2_r = b2[c2];
    const float bo_r = bo[co];

    // delay-buffer slice: channel h, delays q*32 .. q*32+31
    f32x2 buf2[16];
#pragma unroll
    for (int d = 0; d < 16; ++d) { buf2[d].x = 0.f; buf2[d].y = 0.f; }

    __shared__ f32x4 s_x4[T * INPUT / 4];   // 32 KB staged input
    __shared__ float s_vh[140];             // heads, PADH layout (conflict-free)
    __shared__ f32x4 s_msg4[48];            // msg f32, stride-24 per 16
    __shared__ float s_h1[HALF];
    __shared__ f32x4 s_out4[OUT_LEN * OUT / 4];  // 16 KB decode-output stash

    {
        const f32x4* xg4 = (const f32x4*)x;
        for (int idx = tid; idx < T * INPUT / 4; idx += NTHR)
            s_x4[idx] = xg4[b * (T * INPUT / 4) + idx];
        if (tid < 35) ((f32x4*)s_vh)[tid] = splat4(0.f);   // heads = 0 (140 floats)
    }
    __syncthreads();                        // B1 (iter 0)

    // preamble: x-part partial for step 0
    float px = 0.f;
    if (0 < len) {
        const f32x4* xs = s_x4 + q * 4;
        f32x4 t = (wmx[0] * xs[0] + wmx[2] * xs[2]) + (wmx[1] * xs[1] + wmx[3] * xs[3]);
        px = (t.x + t.z) + (t.y + t.w);
    }

    const float ivb = (float)q * 0.25f;     // (q*32)/128
    float msg_p = 0.f, tau_p = 0.f, mem_p = 0.f;  // deferred-blend state (i=0: no-op)
    float sv8 = 0.f;                         // old buf2[8].x saved by P3's blend half

    for (int i = 0; i < total; ++i) {
        // ============ phase 1: heads dot (+ deferred blend half d in [0,8)) ============
        const f32x4* v4 = (const f32x4*)(s_vh + q * 36);
        f32x4 a0 = wmh[0] * v4[0] + wmh[4] * v4[4];
        f32x4 a1 = wmh[1] * v4[1] + wmh[5] * v4[5];
        f32x4 a2 = wmh[2] * v4[2] + wmh[6] * v4[6];
        f32x4 a3 = wmh[3] * v4[3] + wmh[7] * v4[7];

        // ---- blend(i-1) first half: buf2[0..7] (no DPP; d=7 edge uses sv8) ----
        {
            const float taup = tau_p - ivb;
            f32x2 t2; t2.x = taup; t2.y = taup - (1.f / MAX_DELAY);
            const f32x2 st2  = splat2(-2.f / MAX_DELAY);
            const f32x2 mem2 = splat2(mem_p);
            const f32x2 m2m  = splat2(-2.f * mem_p);
            const f32x2 msg2 = splat2(msg_p);
#pragma unroll
            for (int d = 0; d < 8; ++d) {
                f32x2 nb;
                nb.x = buf2[d].y;
                nb.y = (d < 7) ? buf2[d + 1].x : sv8;
                f32x2 a  = __builtin_elementwise_max(t2, -t2);   // |tau' - d/128|
                f32x2 f1 = a * mem2 + m2m;                       // a*mem - 2mem
                f32x2 iw = a * f1 + mem2;                        // mem*(1-a)^2
                f32x2 dd = msg2 - nb;
                buf2[d] = iw * dd + nb;
                t2 = t2 + st2;
            }
        }

        f32x4 s4 = (a0 + a1) + (a2 + a3);
        float p = (s4.x + s4.z) + (s4.y + s4.w) + px;   // + lookahead x-part
        p += dpp_movf<DPP_XOR1>(p);
        p += dpp_movf<DPP_XOR2>(p);                 // all 4 lanes: full K=192 dot
        const float z  = p + bm_r;
        const float e2 = __expf(2.f * z);
        const float msg = 1.f - 2.f * __builtin_amdgcn_rcpf(e2 + 1.f);  // tanh
        if (q == 0) ((float*)s_msg4)[PAD16(h)] = msg;
        msg_p = msg;
        __syncthreads();                            // B2: msg visible block-wide

        // ============ phase 2: h1 + x-lookahead + out-stash ============
        {
            const f32x4* m4 = (const f32x4*)((const float*)s_msg4 + r1 * 24);
            f32x4 cA = w14[0] * m4[0] + w14[2] * m4[2];
            f32x4 cB = w14[1] * m4[1] + w14[3] * m4[3];
            f32x4 cc = cA + cB;
            float p1 = (cc.x + cc.z) + (cc.y + cc.w);
            p1 += dpp_movf<DPP_XOR1>(p1);
            p1 += dpp_movf<DPP_XOR2>(p1);
            p1 += dpp_movf<DPP_MIR8>(p1);           // 8-lane allreduce
            if (r1 == 0) s_h1[k1] = fmaxf(p1 + b1_r, 0.f);
        }

        // ---- x-part lookahead for step i+1 (independent; fills h1 stall) ----
        px = 0.f;
        if (i + 1 < len) {
            const f32x4* xs = s_x4 + (i + 1) * 16 + q * 4;
            f32x4 t = (wmx[0] * xs[0] + wmx[2] * xs[2]) + (wmx[1] * xs[1] + wmx[3] * xs[3]);
            px = (t.x + t.z) + (t.y + t.w);
        }

        // ---- decode out-projection -> LDS stash (no global store in loop) ----
        if (i >= len) {
            const f32x4* mo4 = (const f32x4*)((const float*)s_msg4 + ro * 24);
            f32x4 oA = wo4[0] * mo4[0] + wo4[2] * mo4[2];
            f32x4 oB = wo4[1] * mo4[1] + wo4[3] * mo4[3];
            f32x4 oo = oA + oB;
            float po = (oo.x + oo.z) + (oo.y + oo.w);
            po += dpp_movf<DPP_XOR1>(po);
            po += dpp_movf<DPP_XOR2>(po);
            po += dpp_movf<DPP_MIR8>(po);
            if (ro == 0) ((float*)s_out4)[(i - len) * OUT + co] = po + bo_r;
        }
        __syncthreads();                            // B3: h1 visible block-wide

        // ============ phase 3: tau/mem + head + blend(i) half d in [8,16) ============
        {
            const f32x4* hh4 = (const f32x4*)(s_h1 + (qq << 5));
            f32x4 tA = w24[0] * hh4[0] + w24[2] * hh4[2] + w24[4] * hh4[4] + w24[6] * hh4[6];
            f32x4 tB = w24[1] * hh4[1] + w24[3] * hh4[3] + w24[5] * hh4[5] + w24[7] * hh4[7];
            f32x4 tt = tA + tB;
            float pt = (tt.x + tt.z) + (tt.y + tt.w);
            pt += dpp_movf<DPP_XOR1>(pt);            // K-halves combined
            const float own = __builtin_amdgcn_rcpf(1.f + __expf(-(pt + b2_r)));
            const float oth = dpp_movf<DPP_XOR2>(own);
            const float tau_r = qh ? oth : own;
            const float mem_r = qh ? own : oth;
            tau_p = tau_r; mem_p = mem_r;

            // head (global delay 0) from buf2[0].y (pre-blend(i): buf2[0] updates in P1 next)
            const float nb0 = buf2[0].y;
            const float iw0 = tau_r * (tau_r * mem_r - 2.f * mem_r) + mem_r;  // mem*(1-tau)^2
            const float head = iw0 * (msg_p - nb0) + nb0;
            if (q == 0) s_vh[PADH(h)] = head;

            // ---- blend(i) second half: buf2[8..15] (fills P3's idle issue slots) ----
            float tail_in = dpp_movf<DPP_ROT1>(buf2[0].x);   // neighbor's OLD slice head
            if (q == 3) tail_in = 0.f;                       // shift-in zero at d=127
            sv8 = buf2[8].x;                                 // save old edge for P1's d=7
            const float taup = tau_r - ivb - 8.f / MAX_DELAY;
            f32x2 t2; t2.x = taup; t2.y = taup - (1.f / MAX_DELAY);
            const f32x2 st2  = splat2(-2.f / MAX_DELAY);
            const f32x2 mem2 = splat2(mem_r);
            const f32x2 m2m  = splat2(-2.f * mem_r);
            const f32x2 msg2 = splat2(msg_p);
#pragma unroll
            for (int d = 8; d < 16; ++d) {
                f32x2 nb;
                nb.x = buf2[d].y;
                nb.y = (d < 15) ? buf2[d + 1].x : tail_in;
                f32x2 a  = __builtin_elementwise_max(t2, -t2);
                f32x2 f1 = a * mem2 + m2m;
                f32x2 iw = a * f1 + mem2;
                f32x2 dd = msg2 - nb;
                buf2[d] = iw * dd + nb;
                t2 = t2 + st2;
            }
        }
        __syncthreads();                            // B1 (next iter)
    }

    // ---- bulk store decode outputs (coalesced) ----
    {
        f32x4* og4 = (f32x4*)(out + b * OUT_LEN * OUT);
        og4[tid]        = s_out4[tid];
        og4[tid + NTHR] = s_out4[tid + NTHR];
    }
}

extern "C" void kernel_launch(void* const* d_in, const int* in_sizes, int n_in,
                              void* d_out, int out_size, void* d_ws, size_t ws_size,
                              hipStream_t stream) {
    const float* x       = (const float*)d_in[0];
    const int*   lengths = (const int*)  d_in[1];
    // d_in[2] = out_lengths scalar (compile-time 64)
    const float* Wm = (const float*)d_in[3];
    const float* bm = (const float*)d_in[4];
    const float* W1 = (const float*)d_in[5];
    const float* b1 = (const float*)d_in[6];
    const float* W2 = (const float*)d_in[7];
    const float* b2 = (const float*)d_in[8];
    const float* Wo = (const float*)d_in[9];
    const float* bo = (const float*)d_in[10];
    float* out = (float*)d_out;

    delayrnn_kernel<<<BATCH, NTHR, 0, stream>>>(
        x, lengths, Wm, bm, W1, b1, W2, b2, Wo, bo, out);
}

// Round 13
// 310.328 us; speedup vs baseline: 1.0492x; 1.0492x over previous
//
#include <hip/hip_runtime.h>
#include <math.h>

typedef __attribute__((ext_vector_type(2))) float f32x2;
typedef __attribute__((ext_vector_type(4))) float f32x4;

#define MAX_DELAY 128
#define INPUT 64
#define HIDDEN 128
#define HALF 64
#define OUT 64
#define BATCH 32
#define T 128
#define OUT_LEN 64
#define NTHR 512

static __device__ __forceinline__ f32x2 splat2(float v) { f32x2 r; r.x = v; r.y = v; return r; }
static __device__ __forceinline__ f32x4 splat4(float v) { f32x4 r; r.x = v; r.y = v; r.z = v; r.w = v; return r; }

// DPP cross-lane (1-cycle VALU).
template <int CTRL>
static __device__ __forceinline__ float dpp_movf(float v) {
    return __int_as_float(__builtin_amdgcn_update_dpp(
        0, __float_as_int(v), CTRL, 0xF, 0xF, true));
}
#define DPP_XOR1 0xB1  // quad_perm [1,0,3,2]
#define DPP_XOR2 0x4E  // quad_perm [2,3,0,1]
#define DPP_ROT1 0x39  // quad_perm [1,2,3,0] (lane i <- i+1 mod 4)
#define DPP_MIR8 0x141 // row_half_mirror

// msg LDS pad: stride-24 per 16 floats (conflict-free, x4-aligned)
#define PAD16(k) ((k) + (((k) >> 4) << 3))
// heads LDS pad: +4 floats per 32 -> quad streams hit disjoint bank groups
#define PADH(k)  ((k) + (((k) >> 5) << 2))

// SESSION-BEST STRUCTURE (verified floor: 242.5-244.4 us dispatch, twice).
// 512 thr / 8 waves (2/SIMD), 3 barriers/step — minimum for the dataflow's
// three all-to-all exchanges (heads->msg, msg->h1, h1->tau; relu/tanh block
// algebraic fusion). Cycle model: ~1240 cy issue + 3x~300 cy barrier units
// + chain remainders ~= 3050 cy/iter (matches measurement).
// Probed & rejected: f16 redundant h1 (R1 precision), 16 thin waves (R3),
// blend splits (R5 P1/P2, R12 P1/P3 — both regress; blend must stay WHOLE in
// P1's heads-read shadow), packed-fp32 (R7 neutral), 1 thick wave/SIMD (R8),
// dual-batch (R9), LDS-atomic barrier merge (R10).
// Kept wins: whole-blend deferral into P1 (R2), x-lookahead + LDS out-stash +
// padded layouts (R4), waves_per_eu pin (R6).
__global__ __attribute__((amdgpu_waves_per_eu(2, 2))) __launch_bounds__(NTHR)
void delayrnn_kernel(
    const float* __restrict__ x,        // (B, T, INPUT)
    const int*   __restrict__ lengths,  // (B)
    const float* __restrict__ Wm,       // (INPUT+HIDDEN, HIDDEN)
    const float* __restrict__ bm,       // (HIDDEN)
    const float* __restrict__ W1,       // (HIDDEN, HALF)
    const float* __restrict__ b1,       // (HALF)
    const float* __restrict__ W2,       // (HALF, 2*HIDDEN)
    const float* __restrict__ b2,       // (2*HIDDEN)
    const float* __restrict__ Wo,       // (HIDDEN, OUT)
    const float* __restrict__ bo,       // (OUT)
    float* __restrict__ out)            // (B, OUT_LEN, OUT)
{
    const int b   = blockIdx.x;
    const int tid = threadIdx.x;
    const int len = lengths[b];
    const int total = len + OUT_LEN;

    const int h  = tid >> 2, q  = tid & 3;   // channel h: quad of 4 lanes
    const int qq = q & 1,    qh = q >> 1;    // tau/mem roles within the quad
    const int k1 = tid >> 3, r1 = tid & 7;   // h1: 8 lanes/out
    const int co = tid >> 3, ro = tid & 7;   // out-proj: 8 lanes/out
    const int c2 = h + 128 * qh;             // qh=0: tau col, qh=1: mem col

    // ---- weights -> registers (all f32) ----
    f32x4 wmh[8];                       // msg heads-part: rows 64 + [q*32, q*32+32)
#pragma unroll
    for (int j = 0; j < 8; ++j) {
        wmh[j].x = Wm[(64 + q * 32 + 4 * j    ) * HIDDEN + h];
        wmh[j].y = Wm[(64 + q * 32 + 4 * j + 1) * HIDDEN + h];
        wmh[j].z = Wm[(64 + q * 32 + 4 * j + 2) * HIDDEN + h];
        wmh[j].w = Wm[(64 + q * 32 + 4 * j + 3) * HIDDEN + h];
    }
    f32x4 wmx[4];                       // msg x-part: rows [q*16, q*16+16)
#pragma unroll
    for (int j = 0; j < 4; ++j) {
        wmx[j].x = Wm[(q * 16 + 4 * j    ) * HIDDEN + h];
        wmx[j].y = Wm[(q * 16 + 4 * j + 1) * HIDDEN + h];
        wmx[j].z = Wm[(q * 16 + 4 * j + 2) * HIDDEN + h];
        wmx[j].w = Wm[(q * 16 + 4 * j + 3) * HIDDEN + h];
    }
    f32x4 w14[4];                       // h1: K-slice [r1*16, r1*16+16)
#pragma unroll
    for (int j = 0; j < 4; ++j) {
        w14[j].x = W1[(r1 * 16 + 4 * j    ) * HALF + k1];
        w14[j].y = W1[(r1 * 16 + 4 * j + 1) * HALF + k1];
        w14[j].z = W1[(r1 * 16 + 4 * j + 2) * HALF + k1];
        w14[j].w = W1[(r1 * 16 + 4 * j + 3) * HALF + k1];
    }
    f32x4 w24[8];                       // tau/mem: K-slice [qq*32, qq*32+32)
#pragma unroll
    for (int j = 0; j < 8; ++j) {
        w24[j].x = W2[(qq * 32 + 4 * j    ) * (2 * HIDDEN) + c2];
        w24[j].y = W2[(qq * 32 + 4 * j + 1) * (2 * HIDDEN) + c2];
        w24[j].z = W2[(qq * 32 + 4 * j + 2) * (2 * HIDDEN) + c2];
        w24[j].w = W2[(qq * 32 + 4 * j + 3) * (2 * HIDDEN) + c2];
    }
    f32x4 wo4[4];                       // out: K-slice [ro*16, ro*16+16)
#pragma unroll
    for (int m = 0; m < 4; ++m) {
        wo4[m].x = Wo[(ro * 16 + 4 * m    ) * OUT + co];
        wo4[m].y = Wo[(ro * 16 + 4 * m + 1) * OUT + co];
        wo4[m].z = Wo[(ro * 16 + 4 * m + 2) * OUT + co];
        wo4[m].w = Wo[(ro * 16 + 4 * m + 3) * OUT + co];
    }
    const float bm_r = bm[h];
    const float b1_r = b1[k1];
    const float b2_r = b2[c2];
    const float bo_r = bo[co];

    // delay-buffer slice: channel h, delays q*32 .. q*32+31
    f32x2 buf2[16];
#pragma unroll
    for (int d = 0; d < 16; ++d) { buf2[d].x = 0.f; buf2[d].y = 0.f; }

    __shared__ f32x4 s_x4[T * INPUT / 4];   // 32 KB staged input
    __shared__ float s_vh[140];             // heads, PADH layout (conflict-free)
    __shared__ f32x4 s_msg4[48];            // msg f32, stride-24 per 16
    __shared__ float s_h1[HALF];
    __shared__ f32x4 s_out4[OUT_LEN * OUT / 4];  // 16 KB decode-output stash

    {
        const f32x4* xg4 = (const f32x4*)x;
        for (int idx = tid; idx < T * INPUT / 4; idx += NTHR)
            s_x4[idx] = xg4[b * (T * INPUT / 4) + idx];
        if (tid < 35) ((f32x4*)s_vh)[tid] = splat4(0.f);   // heads = 0 (140 floats)
    }
    __syncthreads();                        // B1 (iter 0)

    // preamble: x-part partial for step 0
    float px = 0.f;
    if (0 < len) {
        const f32x4* xs = s_x4 + q * 4;
        f32x4 t = (wmx[0] * xs[0] + wmx[2] * xs[2]) + (wmx[1] * xs[1] + wmx[3] * xs[3]);
        px = (t.x + t.z) + (t.y + t.w);
    }

    const float ivb = (float)q * 0.25f;     // (q*32)/128
    float msg_p = 0.f, tau_p = 0.f, mem_p = 0.f;  // deferred-blend state (i=0: no-op)

    for (int i = 0; i < total; ++i) {
        // ============ phase 1: heads dot (+ deferred blend of step i-1) ============
        const f32x4* v4 = (const f32x4*)(s_vh + q * 36);
        f32x4 a0 = wmh[0] * v4[0] + wmh[4] * v4[4];
        f32x4 a1 = wmh[1] * v4[1] + wmh[5] * v4[5];
        f32x4 a2 = wmh[2] * v4[2] + wmh[6] * v4[6];
        f32x4 a3 = wmh[3] * v4[3] + wmh[7] * v4[7];

        // ---- deferred blend of step i-1 (independent VALU; fills the LDS-read stall) ----
        {
            float tail_in = dpp_movf<DPP_ROT1>(buf2[0].x);   // neighbor q+1's old head
            if (q == 3) tail_in = 0.f;                       // shift-in zero at d=127
            const float taup = tau_p - ivb;
            f32x2 t2; t2.x = taup; t2.y = taup - (1.f / MAX_DELAY);
            const f32x2 st2  = splat2(-2.f / MAX_DELAY);
            const f32x2 mem2 = splat2(mem_p);
            const f32x2 m2m  = splat2(-2.f * mem_p);
            const f32x2 msg2 = splat2(msg_p);
#pragma unroll
            for (int d = 0; d < 16; ++d) {
                f32x2 nb;
                nb.x = buf2[d].y;
                nb.y = (d < 15) ? buf2[d + 1].x : tail_in;
                f32x2 a  = __builtin_elementwise_max(t2, -t2);   // |tau' - d/128|
                f32x2 f1 = a * mem2 + m2m;                       // a*mem - 2mem
                f32x2 iw = a * f1 + mem2;                        // mem*(1-a)^2
                f32x2 dd = msg2 - nb;
                buf2[d] = iw * dd + nb;
                t2 = t2 + st2;
            }
        }

        f32x4 s4 = (a0 + a1) + (a2 + a3);
        float p = (s4.x + s4.z) + (s4.y + s4.w) + px;   // + lookahead x-part
        p += dpp_movf<DPP_XOR1>(p);
        p += dpp_movf<DPP_XOR2>(p);                 // all 4 lanes: full K=192 dot
        const float z  = p + bm_r;
        const float e2 = __expf(2.f * z);
        const float msg = 1.f - 2.f * __builtin_amdgcn_rcpf(e2 + 1.f);  // tanh
        if (q == 0) ((float*)s_msg4)[PAD16(h)] = msg;
        msg_p = msg;
        __syncthreads();                            // B2: msg visible block-wide

        // ============ phase 2: h1 + x-lookahead + out-stash ============
        {
            const f32x4* m4 = (const f32x4*)((const float*)s_msg4 + r1 * 24);
            f32x4 cA = w14[0] * m4[0] + w14[2] * m4[2];
            f32x4 cB = w14[1] * m4[1] + w14[3] * m4[3];
            f32x4 cc = cA + cB;
            float p1 = (cc.x + cc.z) + (cc.y + cc.w);
            p1 += dpp_movf<DPP_XOR1>(p1);
            p1 += dpp_movf<DPP_XOR2>(p1);
            p1 += dpp_movf<DPP_MIR8>(p1);           // 8-lane allreduce
            if (r1 == 0) s_h1[k1] = fmaxf(p1 + b1_r, 0.f);
        }

        // ---- x-part lookahead for step i+1 (independent; fills h1 stall) ----
        px = 0.f;
        if (i + 1 < len) {
            const f32x4* xs = s_x4 + (i + 1) * 16 + q * 4;
            f32x4 t = (wmx[0] * xs[0] + wmx[2] * xs[2]) + (wmx[1] * xs[1] + wmx[3] * xs[3]);
            px = (t.x + t.z) + (t.y + t.w);
        }

        // ---- decode out-projection -> LDS stash (no global store in loop) ----
        if (i >= len) {
            const f32x4* mo4 = (const f32x4*)((const float*)s_msg4 + ro * 24);
            f32x4 oA = wo4[0] * mo4[0] + wo4[2] * mo4[2];
            f32x4 oB = wo4[1] * mo4[1] + wo4[3] * mo4[3];
            f32x4 oo = oA + oB;
            float po = (oo.x + oo.z) + (oo.y + oo.w);
            po += dpp_movf<DPP_XOR1>(po);
            po += dpp_movf<DPP_XOR2>(po);
            po += dpp_movf<DPP_MIR8>(po);
            if (ro == 0) ((float*)s_out4)[(i - len) * OUT + co] = po + bo_r;
        }
        __syncthreads();                            // B3: h1 visible block-wide

        // ============ phase 3: tau/mem + head only (blend deferred) ============
        {
            const f32x4* hh4 = (const f32x4*)(s_h1 + (qq << 5));
            f32x4 tA = w24[0] * hh4[0] + w24[2] * hh4[2] + w24[4] * hh4[4] + w24[6] * hh4[6];
            f32x4 tB = w24[1] * hh4[1] + w24[3] * hh4[3] + w24[5] * hh4[5] + w24[7] * hh4[7];
            f32x4 tt = tA + tB;
            float pt = (tt.x + tt.z) + (tt.y + tt.w);
            pt += dpp_movf<DPP_XOR1>(pt);            // K-halves combined
            const float own = __builtin_amdgcn_rcpf(1.f + __expf(-(pt + b2_r)));
            const float oth = dpp_movf<DPP_XOR2>(own);
            const float tau_r = qh ? oth : own;
            const float mem_r = qh ? own : oth;
            tau_p = tau_r; mem_p = mem_r;

            // head (global delay 0) from post-blend(i-1) buf[1]; full blend deferred
            const float nb0 = buf2[0].y;
            const float iw0 = tau_r * (tau_r * mem_r - 2.f * mem_r) + mem_r;  // mem*(1-tau)^2
            const float head = iw0 * (msg_p - nb0) + nb0;
            if (q == 0) s_vh[PADH(h)] = head;
        }
        __syncthreads();                            // B1 (next iter)
    }

    // ---- bulk store decode outputs (coalesced) ----
    {
        f32x4* og4 = (f32x4*)(out + b * OUT_LEN * OUT);
        og4[tid]        = s_out4[tid];
        og4[tid + NTHR] = s_out4[tid + NTHR];
    }
}

extern "C" void kernel_launch(void* const* d_in, const int* in_sizes, int n_in,
                              void* d_out, int out_size, void* d_ws, size_t ws_size,
                              hipStream_t stream) {
    const float* x       = (const float*)d_in[0];
    const int*   lengths = (const int*)  d_in[1];
    // d_in[2] = out_lengths scalar (compile-time 64)
    const float* Wm = (const float*)d_in[3];
    const float* bm = (const float*)d_in[4];
    const float* W1 = (const float*)d_in[5];
    const float* b1 = (const float*)d_in[6];
    const float* W2 = (const float*)d_in[7];
    const float* b2 = (const float*)d_in[8];
    const float* Wo = (const float*)d_in[9];
    const float* bo = (const float*)d_in[10];
    float* out = (float*)d_out;

    delayrnn_kernel<<<BATCH, NTHR, 0, stream>>>(
        x, lengths, Wm, bm, W1, b1, W2, b2, Wo, bo, out);
}